// Round 1
// 223.536 us; speedup vs baseline: 1.0088x; 1.0088x over previous
//
#include <hip/hip_runtime.h>
#include <math.h>

// B=2048, N=8192, fp32. One block per row, 256 threads, 32 elems/thread.
#define N_COLS 8192
#define BLOCK  256
#define NW     4                   // waves per block
#define F4PT   (N_COLS / BLOCK / 4) // float4 groups per thread = 8
#define NBINS  1024
#define BPL    (NBINS / 64)        // bins per lane in the Newton wave = 16

// d_out[0] must be zeroed every call (harness re-poisons to 0xAA).
__global__ void zero_out_kernel(float* out) {
    if (threadIdx.x == 0 && blockIdx.x == 0) out[0] = 0.0f;
}

__global__ __launch_bounds__(BLOCK) void custom_loss_kernel(
        const float* __restrict__ y_pred,
        const float* __restrict__ y_true,
        const float* __restrict__ Lambda,
        float* __restrict__ out,      // out[0]=loss, out[1..]=updated_Lambda
        float inv_total) {
    __shared__ unsigned int s_hist[NBINS];   // count-only histogram of r
    __shared__ float s_wmax[NW];
    __shared__ float s_part[NW];
    __shared__ float s_bcast[2];             // {beta, inv_qmax}

    const int row  = blockIdx.x;
    const int tid  = threadIdx.x;
    const int lane = tid & 63;
    const int wid  = tid >> 6;
    const size_t base = (size_t)row * N_COLS;
    const float4* yp4 = (const float4*)(y_pred + base);  // rows are 32KB-aligned
    const float4* yt4 = (const float4*)(y_true + base);

    // ---- pass 1: residuals in registers (float4 layout), local max ----
    float4 r[F4PT];
    float rmax = 0.0f;
    #pragma unroll
    for (int j = 0; j < F4PT; ++j) {
        const int g = j * BLOCK + tid;       // coalesced float4
        float4 a = yt4[g];
        float4 b = yp4[g];
        float4 rv;
        rv.x = fabsf(a.x - b.x); rv.y = fabsf(a.y - b.y);
        rv.z = fabsf(a.z - b.z); rv.w = fabsf(a.w - b.w);
        r[j] = rv;
        rmax = fmaxf(rmax, fmaxf(fmaxf(rv.x, rv.y), fmaxf(rv.z, rv.w)));
    }
    // wave-level max
    #pragma unroll
    for (int m = 32; m >= 1; m >>= 1) rmax = fmaxf(rmax, __shfl_xor(rmax, m, 64));
    if (lane == 0) s_wmax[wid] = rmax;
    // zero histogram before the single barrier (no hazard: atomics come after)
    #pragma unroll
    for (int i = 0; i < NBINS / BLOCK; ++i) s_hist[tid + i * BLOCK] = 0u;
    __syncthreads();                          // hist zeroed + s_wmax visible
    rmax = fmaxf(fmaxf(s_wmax[0], s_wmax[1]), fmaxf(s_wmax[2], s_wmax[3]));
    rmax = fmaxf(rmax, 1e-8f);

    // ---- pass 2: histogram of r (count only; bin centers are the proxy) ----
    const float hscale = (float)NBINS / rmax;
    #pragma unroll
    for (int j = 0; j < F4PT; ++j) {
        unsigned bx = min((unsigned)(r[j].x * hscale), (unsigned)(NBINS - 1));
        unsigned by = min((unsigned)(r[j].y * hscale), (unsigned)(NBINS - 1));
        unsigned bz = min((unsigned)(r[j].z * hscale), (unsigned)(NBINS - 1));
        unsigned bw = min((unsigned)(r[j].w * hscale), (unsigned)(NBINS - 1));
        atomicAdd(&s_hist[bx], 1u);
        atomicAdd(&s_hist[by], 1u);
        atomicAdd(&s_hist[bz], 1u);
        atomicAdd(&s_hist[bw], 1u);
    }
    __syncthreads();                          // histogram complete

    // ---- prefetch Lambda NOW: the 64MB stream + its latency overlap the
    //      Newton solve below (HBM otherwise idle during that phase) ----
    const float4* lam4 = (const float4*)(Lambda + base);
    float4 lam[F4PT];
    #pragma unroll
    for (int j = 0; j < F4PT; ++j) lam[j] = lam4[j * BLOCK + tid];

    // ---- Newton on the 1024-bin histogram: wave 0 only, no barriers ----
    // Bins are equally spaced: u_b = (b+0.5)*d, so exp(u_{b+64}) =
    // exp(u_b)*exp(64d). Running products replace 2 exps/bin with 2 muls/bin.
    if (wid == 0) {
        float eps = rmax / (logf(2.0f * (float)N_COLS) + 1e-8f);
        const float binw = rmax * (1.0f / (float)NBINS);
        const float sc2  = 0.5f / (float)N_COLS;   // 2^-14 exact
        for (int it = 0; it < 20; ++it) {
            const float inv_eps = __builtin_amdgcn_rcpf(fmaxf(eps, 1e-8f));
            const float d   = binw * inv_eps;       // per-bin u step
            const float d64 = 64.0f * d;            // per-k u step (this lane)
            float u  = ((float)lane + 0.5f) * d;    // u of bin 'lane'
            float e  = __expf(u);                   // running exp(+u)
            float ei = __expf(-u);                  // running exp(-u)
            const float E  = __expf(d64);           // geometric ratios
            const float Ei = __expf(-d64);
            float fs = 0.0f, gs = 0.0f;     // Σ n*(e-ei), Σ n*(e+ei)*u
            #pragma unroll
            for (int k = 0; k < BPL; ++k) {
                const float n = (float)s_hist[lane + 64 * k]; // conflict-free
                fs = fmaf(n, e - ei, fs);
                gs = fmaf(n * (e + ei), u, gs);
                e *= E; ei *= Ei; u += d64;
            }
            #pragma unroll
            for (int m2 = 32; m2 >= 1; m2 >>= 1) {
                fs += __shfl_xor(fs, m2, 64);
                gs += __shfl_xor(gs, m2, 64);
            }
            float val  = fmaf(fs, sc2, -1.0f);          // mean(sinh)-1
            float grad = -(gs * sc2) * inv_eps;         // mean(cosh*(-u/eps))
            float delta = val * __builtin_amdgcn_rcpf(grad - 1e-8f);
            eps -= delta;
            if (fabsf(delta) <= 1e-5f * eps) break;     // wave-uniform
        }
        eps = fmaxf(eps, 1e-8f);
        const float beta = 1.0f / (eps + 1e-6f);
        // qmax = sinh(beta*rmax) analytically (sinh is monotone increasing)
        const float um = beta * rmax;
        const float qmax = 0.5f * (__expf(um) - __expf(-um));
        if (lane == 0) {
            s_bcast[0] = beta;
            s_bcast[1] = 1.0f / (qmax + 1e-20f);
        }
    }
    __syncthreads();
    const float beta     = s_bcast[0];
    const float inv_qmax = s_bcast[1];

    // ---- epilogue: q=sinh(beta*r), EMA update, store, loss partial ----
    // (Lambda already in registers; this phase is store-only on the mem side)
    float* outw = out + 1 + base;   // 4B-aligned only -> scalar stores
    float s_loss = 0.0f;
    #pragma unroll
    for (int j = 0; j < F4PT; ++j) {
        const int g = j * BLOCK + tid;
        float rr[4] = {r[j].x, r[j].y, r[j].z, r[j].w};
        float LL[4] = {lam[j].x, lam[j].y, lam[j].z, lam[j].w};
        #pragma unroll
        for (int c = 0; c < 4; ++c) {
            float u  = beta * rr[c];
            float q  = 0.5f * (__expf(u) - __expf(-u));
            float lam_it = fmaf(0.9f, q * inv_qmax, 0.1f);  // PHI, 1-PHI
            float uL = fmaf(0.99f, LL[c], 0.1f * lam_it);   // GAMMA, ETA
            outw[(size_t)g * 4 + c] = uL;
            float t = uL * rr[c];
            s_loss = fmaf(t, t, s_loss);
        }
    }
    #pragma unroll
    for (int m = 32; m >= 1; m >>= 1) s_loss += __shfl_xor(s_loss, m, 64);
    if (lane == 0) s_part[wid] = s_loss;    // first use of s_part: no pre-barrier
    __syncthreads();
    if (tid == 0) {
        float tot = (s_part[0] + s_part[1]) + (s_part[2] + s_part[3]);
        atomicAdd(out, tot * inv_total);
    }
}

extern "C" void kernel_launch(void* const* d_in, const int* in_sizes, int n_in,
                              void* d_out, int out_size, void* d_ws, size_t ws_size,
                              hipStream_t stream) {
    const float* y_pred = (const float*)d_in[0];
    const float* y_true = (const float*)d_in[1];
    const float* Lambda = (const float*)d_in[2];
    float* out = (float*)d_out;

    const int total = in_sizes[0];            // B * N
    const int B = total / N_COLS;
    const float inv_total = 1.0f / (float)total;

    hipLaunchKernelGGL(zero_out_kernel, dim3(1), dim3(64), 0, stream, out);
    hipLaunchKernelGGL(custom_loss_kernel, dim3(B), dim3(BLOCK), 0, stream,
                       y_pred, y_true, Lambda, out, inv_total);
}